// Round 13
// baseline (474.800 us; speedup 1.0000x reference)
//
#include <hip/hip_runtime.h>

#define TOK 64
#define CDIM 192
#define NH 6
#define HD 32
#define THREADS 384
#define GRID_MAX 512
#define QSCALE 0.17677669529663687f  // 32^-0.5

// workspace layout (halfs): w_qkv16 [576*192] | w_proj16 [192*192] | bias frags [6*4*64*16]
#define WQ16_OFF 0
#define WP16_OFF 110592
#define BIAS_OFF 147456
#define WS_HALFS (147456 + 24576)
#define WS_BYTES (WS_HALFS * 2)

typedef _Float16 f16x8 __attribute__((ext_vector_type(8)));
typedef _Float16 f16x4 __attribute__((ext_vector_type(4)));
typedef float f32x4 __attribute__((ext_vector_type(4)));

__device__ __forceinline__ f16x8 ld8(const _Float16* p) {
  return *reinterpret_cast<const f16x8*>(p);
}

__device__ __forceinline__ f16x8 cvt8(const float* __restrict__ p) {
  float4 a = *reinterpret_cast<const float4*>(p);
  float4 c = *reinterpret_cast<const float4*>(p + 4);
  f16x8 r;
  r[0] = (_Float16)a.x; r[1] = (_Float16)a.y; r[2] = (_Float16)a.z; r[3] = (_Float16)a.w;
  r[4] = (_Float16)c.x; r[5] = (_Float16)c.y; r[6] = (_Float16)c.z; r[7] = (_Float16)c.w;
  return r;
}

__device__ __forceinline__ f16x8 cvt2(float4 a, float4 c) {
  f16x8 r;
  r[0] = (_Float16)a.x; r[1] = (_Float16)a.y; r[2] = (_Float16)a.z; r[3] = (_Float16)a.w;
  r[4] = (_Float16)c.x; r[5] = (_Float16)c.y; r[6] = (_Float16)c.z; r[7] = (_Float16)c.w;
  return r;
}

__device__ __forceinline__ f16x4 pack4(float a, float b, float c, float d) {
  f16x4 r;
  r[0] = (_Float16)a; r[1] = (_Float16)b; r[2] = (_Float16)c; r[3] = (_Float16)d;
  return r;
}

// Prologue: fp16 weights + per-(head,row-tile) bias fragments (two f16x8 per lane).
__global__ void prep_ws(const float* __restrict__ wq, const float* __restrict__ wp,
                        const float* __restrict__ bt, _Float16* __restrict__ ws) {
  int i = blockIdx.x * 256 + threadIdx.x;
  if (i < 27648) {
    float4 v = reinterpret_cast<const float4*>(wq)[i];
    f16x4 h;
    h[0] = (_Float16)v.x; h[1] = (_Float16)v.y; h[2] = (_Float16)v.z; h[3] = (_Float16)v.w;
    *reinterpret_cast<f16x4*>(ws + WQ16_OFF + (size_t)i * 4) = h;
  } else if (i < 36864) {
    int j = i - 27648;
    float4 v = reinterpret_cast<const float4*>(wp)[j];
    f16x4 h;
    h[0] = (_Float16)v.x; h[1] = (_Float16)v.y; h[2] = (_Float16)v.z; h[3] = (_Float16)v.w;
    *reinterpret_cast<f16x4*>(ws + WP16_OFF + (size_t)j * 4) = h;
  } else if (i < 61440) {
    int j = i - 36864;            // ((h*4+it)*64 + lane)*16 + (jt*4+r)
    int hit = j >> 10;
    int l = (j >> 4) & 63;
    int s = j & 15;
    int h = hit >> 2, it = hit & 3;
    int ii = it * 16 + (l & 15);
    int jj = (s >> 2) * 16 + (l >> 4) * 4 + (s & 3);
    int rel = ((ii >> 3) - (jj >> 3) + 7) * 15 + ((ii & 7) - (jj & 7) + 7);
    ws[BIAS_OFF + j] = (_Float16)bt[rel * NH + h];
  }
}

// Persistent transpose-free fused window attention.
// Grid = min(B,512) blocks (2/CU); each block loops over B/G windows with a
// double-buffered 2x24 KB LDS x/O region:
//   window i: QKV (merged q+k, then v) -> b1 -> attention (in-reg) -> b2 ->
//             [issue window i+1 x loads] proj (swapped, float4 stores)
//             [cvt+ds_write staged x -> other buffer] -> b3 -> swap.
// HBM staging latency hides under proj; block launch/addressing/I-cache
// amortize over 8 windows. 3 barriers per window.
// Key identity (mfma_f32_16x16x16_f16): A/B k-slice per lane ((l>>4)*4..+3)
// equals D-row indexing -> packed D fragments feed attention MFMAs directly.
// Swapped proj: A/B fragments have identical data layout, so the same LDS
// O-panel ld8 serves as B-operand; D then has lane=token, regs=consecutive e
// -> coalesced float4 stores.
template <bool WS>
__global__ __launch_bounds__(THREADS, 4) void winattn(
    const float* __restrict__ x, const float* __restrict__ w_qkv,
    const float* __restrict__ b_qkv, const float* __restrict__ w_proj,
    const float* __restrict__ b_proj, const float* __restrict__ bias_table,
    const _Float16* __restrict__ ws, float* __restrict__ out, int B) {
  __shared__ __align__(16) _Float16 X[2][12288];  // x panels -> O panels, x2

  const int tid = threadIdx.x;
  const int h   = tid >> 6;   // wave == head (0..5)
  const int l   = tid & 63;
  const int l15 = l & 15;
  const int lg  = l >> 4;
  const int sA0 = l15 ^ lg;
  const int sA1 = sA0 ^ 4;
  const int G   = gridDim.x;
  const f32x4 vzero = {0.f, 0.f, 0.f, 0.f};

  // staging geometry (loop-invariant): chunk q -> token n, c-panel pp
  int goff[4], soff[4];
#pragma unroll
  for (int kk = 0; kk < 4; ++kk) {
    int q = tid + kk * THREADS;
    int n = q / 24;
    int pp = q - n * 24;
    goff[kk] = q * 8;
    soff[kk] = (pp * TOK + (n ^ (pp & 7))) * 8;
  }

  // weight pointers (loop-invariant)
  const _Float16 *pq0 = nullptr, *pq1 = nullptr, *pk0 = nullptr, *pk1 = nullptr,
                 *pv0 = nullptr, *pv1 = nullptr, *pw0 = nullptr, *pw1 = nullptr;
  const float *fq0 = nullptr, *fq1 = nullptr, *fk0 = nullptr, *fk1 = nullptr,
              *fv0 = nullptr, *fv1 = nullptr, *fw0 = nullptr, *fw1 = nullptr;
  if constexpr (WS) {
    pq0 = ws + WQ16_OFF + (size_t)(h * HD + l15) * CDIM + lg * 8;
    pq1 = pq0 + (size_t)16 * CDIM;
    pk0 = pq0 + (size_t)CDIM * CDIM;
    pk1 = pk0 + (size_t)16 * CDIM;
    pv0 = pq0 + (size_t)2 * CDIM * CDIM;
    pv1 = pv0 + (size_t)16 * CDIM;
    pw0 = ws + WP16_OFF + (size_t)(h * 16 + l15) * CDIM + lg * 8;
    pw1 = pw0 + (size_t)96 * CDIM;
  } else {
    fq0 = w_qkv + (size_t)(h * HD + l15) * CDIM + lg * 8;
    fq1 = fq0 + (size_t)16 * CDIM;
    fk0 = fq0 + (size_t)CDIM * CDIM;
    fk1 = fk0 + (size_t)16 * CDIM;
    fv0 = fq0 + (size_t)2 * CDIM * CDIM;
    fv1 = fv0 + (size_t)16 * CDIM;
    fw0 = w_proj + (size_t)(h * 16 + l15) * CDIM + lg * 8;
    fw1 = fw0 + (size_t)96 * CDIM;
  }

  // ---- prologue: stage window blockIdx.x into X[0] ----
  {
    const float* xg = x + (size_t)blockIdx.x * (TOK * CDIM);
#pragma unroll
    for (int kk = 0; kk < 4; ++kk) {
      float4 v0 = *reinterpret_cast<const float4*>(xg + goff[kk]);
      float4 v1 = *reinterpret_cast<const float4*>(xg + goff[kk] + 4);
      *reinterpret_cast<f16x8*>(&X[0][soff[kk]]) = cvt2(v0, v1);
    }
  }
  __syncthreads();

  int p = 0;
  const int NW = (B + G - 1) / G;
#pragma unroll 1
  for (int wi = 0; wi < NW; ++wi) {
    const int win = blockIdx.x + wi * G;
    if (win >= B) break;
    _Float16* Xa = X[p];
    const _Float16* bxb0 = &Xa[(lg * TOK + sA0) * 8];
    const _Float16* bxb1 = &Xa[(lg * TOK + sA1) * 8];

    // ------- merged q+k GEMM, swapped: D lane = token, rows = d -------
    f32x4 aq[2][4], ak[2][4];
#pragma unroll
    for (int mt = 0; mt < 2; ++mt)
#pragma unroll
      for (int nt = 0; nt < 4; ++nt) { aq[mt][nt] = vzero; ak[mt][nt] = vzero; }
#pragma unroll
    for (int ks = 0; ks < 6; ++ks) {
      const _Float16* bb = (ks & 1) ? bxb1 : bxb0;
      f16x8 bx[4];
#pragma unroll
      for (int nt = 0; nt < 4; ++nt)
        bx[nt] = ld8(bb + ks * 2048 + nt * 128);
      f16x8 wqa[2], wka[2];
      if constexpr (WS) {
        wqa[0] = ld8(pq0 + ks * 32); wqa[1] = ld8(pq1 + ks * 32);
        wka[0] = ld8(pk0 + ks * 32); wka[1] = ld8(pk1 + ks * 32);
      } else {
        wqa[0] = cvt8(fq0 + ks * 32); wqa[1] = cvt8(fq1 + ks * 32);
        wka[0] = cvt8(fk0 + ks * 32); wka[1] = cvt8(fk1 + ks * 32);
      }
      __builtin_amdgcn_s_setprio(1);
#pragma unroll
      for (int mt = 0; mt < 2; ++mt)
#pragma unroll
        for (int nt = 0; nt < 4; ++nt) {
          aq[mt][nt] = __builtin_amdgcn_mfma_f32_16x16x32_f16(wqa[mt], bx[nt], aq[mt][nt], 0, 0, 0);
          ak[mt][nt] = __builtin_amdgcn_mfma_f32_16x16x32_f16(wka[mt], bx[nt], ak[mt][nt], 0, 0, 0);
        }
      __builtin_amdgcn_s_setprio(0);
    }
    f16x4 qp[2][4], kp[2][4];  // lane = token, elems = d (lg*4+r)
#pragma unroll
    for (int mt = 0; mt < 2; ++mt) {
      float4 bq = *reinterpret_cast<const float4*>(b_qkv + h * HD + mt * 16 + lg * 4);
      float4 bk = *reinterpret_cast<const float4*>(b_qkv + CDIM + h * HD + mt * 16 + lg * 4);
#pragma unroll
      for (int nt = 0; nt < 4; ++nt) {
        qp[mt][nt] = pack4((aq[mt][nt][0] + bq.x) * QSCALE, (aq[mt][nt][1] + bq.y) * QSCALE,
                           (aq[mt][nt][2] + bq.z) * QSCALE, (aq[mt][nt][3] + bq.w) * QSCALE);
        kp[mt][nt] = pack4(ak[mt][nt][0] + bk.x, ak[mt][nt][1] + bk.y,
                           ak[mt][nt][2] + bk.z, ak[mt][nt][3] + bk.w);
      }
    }

    // ------- v GEMM, standard (lane = d, rows = kv), both ct merged -------
    f16x4 vp[4][2];
    {
      f32x4 av[4][2];
#pragma unroll
      for (int mt = 0; mt < 4; ++mt)
#pragma unroll
        for (int ct = 0; ct < 2; ++ct) av[mt][ct] = vzero;
#pragma unroll
      for (int ks = 0; ks < 6; ++ks) {
        const _Float16* bb = (ks & 1) ? bxb1 : bxb0;
        f16x8 a[4];
#pragma unroll
        for (int mt = 0; mt < 4; ++mt)
          a[mt] = ld8(bb + ks * 2048 + mt * 128);
        f16x8 bw[2];
        if constexpr (WS) { bw[0] = ld8(pv0 + ks * 32); bw[1] = ld8(pv1 + ks * 32); }
        else              { bw[0] = cvt8(fv0 + ks * 32); bw[1] = cvt8(fv1 + ks * 32); }
        __builtin_amdgcn_s_setprio(1);
#pragma unroll
        for (int mt = 0; mt < 4; ++mt)
#pragma unroll
          for (int ct = 0; ct < 2; ++ct)
            av[mt][ct] = __builtin_amdgcn_mfma_f32_16x16x32_f16(a[mt], bw[ct], av[mt][ct], 0, 0, 0);
        __builtin_amdgcn_s_setprio(0);
      }
      float bv0 = b_qkv[2 * CDIM + h * HD + l15];
      float bv1 = b_qkv[2 * CDIM + h * HD + 16 + l15];
#pragma unroll
      for (int s = 0; s < 4; ++s) {
        vp[s][0] = pack4(av[s][0][0] + bv0, av[s][0][1] + bv0, av[s][0][2] + bv0, av[s][0][3] + bv0);
        vp[s][1] = pack4(av[s][1][0] + bv1, av[s][1][1] + bv1, av[s][1][2] + bv1, av[s][1][3] + bv1);
      }
    }
    __syncthreads();  // b1: x reads done -> Xa free for O

    // ------- attention: 4 row-tiles, all in-register -------
#pragma unroll
    for (int it = 0; it < 4; ++it) {
      f32x4 st[4];
      __builtin_amdgcn_s_setprio(1);
#pragma unroll
      for (int jt = 0; jt < 4; ++jt) {
        st[jt] = __builtin_amdgcn_mfma_f32_16x16x16f16(kp[0][jt], qp[0][it], vzero, 0, 0, 0);
        st[jt] = __builtin_amdgcn_mfma_f32_16x16x16f16(kp[1][jt], qp[1][it], st[jt], 0, 0, 0);
      }
      __builtin_amdgcn_s_setprio(0);
      if constexpr (WS) {
        const _Float16* bw = ws + BIAS_OFF + ((h * 4 + it) * 64 + l) * 16;
        f16x8 b0 = ld8(bw), b1 = ld8(bw + 8);
#pragma unroll
        for (int jt = 0; jt < 4; ++jt)
#pragma unroll
          for (int r = 0; r < 4; ++r)
            st[jt][r] += (float)((jt < 2) ? b0[jt * 4 + r] : b1[(jt - 2) * 4 + r]);
      } else {
        int i = it * 16 + l15, yi = i >> 3, xi = i & 7;
#pragma unroll
        for (int jt = 0; jt < 4; ++jt)
#pragma unroll
          for (int r = 0; r < 4; ++r) {
            int j = jt * 16 + lg * 4 + r, yj = j >> 3, xj = j & 7;
            st[jt][r] += bias_table[(((yi - yj + 7) * 15 + (xi - xj + 7)) * NH + h)];
          }
      }
      float m = st[0][0];
#pragma unroll
      for (int jt = 0; jt < 4; ++jt)
#pragma unroll
        for (int r = 0; r < 4; ++r) m = fmaxf(m, st[jt][r]);
      m = fmaxf(m, __shfl_xor(m, 16, 64));
      m = fmaxf(m, __shfl_xor(m, 32, 64));
      float sum = 0.f;
#pragma unroll
      for (int jt = 0; jt < 4; ++jt)
#pragma unroll
        for (int r = 0; r < 4; ++r) { st[jt][r] = __expf(st[jt][r] - m); sum += st[jt][r]; }
      sum += __shfl_xor(sum, 16, 64);
      sum += __shfl_xor(sum, 32, 64);
      float inv = 1.f / sum;
      f32x4 o[2] = {vzero, vzero};
#pragma unroll
      for (int s = 0; s < 4; ++s) {
        f16x4 pp2 = pack4(st[s][0] * inv, st[s][1] * inv, st[s][2] * inv, st[s][3] * inv);
        __builtin_amdgcn_s_setprio(1);
        o[0] = __builtin_amdgcn_mfma_f32_16x16x16f16(pp2, vp[s][0], o[0], 0, 0, 0);
        o[1] = __builtin_amdgcn_mfma_f32_16x16x16f16(pp2, vp[s][1], o[1], 0, 0, 0);
        __builtin_amdgcn_s_setprio(0);
      }
      // O -> Xa swizzled panels (lane = d col, rows = q-token)
#pragma unroll
      for (int ct = 0; ct < 2; ++ct) {
        int c = h * HD + ct * 16 + l15;
        int op = c >> 3, s7 = op & 7;
        int lgx = lg ^ (s7 >> 2);
        int base = (op * TOK + it * 16 + lgx * 4) * 8 + (c & 7);
#pragma unroll
        for (int r = 0; r < 4; ++r)
          Xa[base + (r ^ (s7 & 3)) * 8] = (_Float16)o[ct][r];
      }
    }
    __syncthreads();  // b2: O visible

    // ------- prefetch next window's x (issue loads; cvt+write after proj) -------
    const int win2 = win + G;
    float4 pf0a, pf0b, pf1a, pf1b, pf2a, pf2b, pf3a, pf3b;
    if (win2 < B) {
      const float* xg2 = x + (size_t)win2 * (TOK * CDIM);
      pf0a = *reinterpret_cast<const float4*>(xg2 + goff[0]);
      pf0b = *reinterpret_cast<const float4*>(xg2 + goff[0] + 4);
      pf1a = *reinterpret_cast<const float4*>(xg2 + goff[1]);
      pf1b = *reinterpret_cast<const float4*>(xg2 + goff[1] + 4);
      pf2a = *reinterpret_cast<const float4*>(xg2 + goff[2]);
      pf2b = *reinterpret_cast<const float4*>(xg2 + goff[2] + 4);
      pf3a = *reinterpret_cast<const float4*>(xg2 + goff[3]);
      pf3b = *reinterpret_cast<const float4*>(xg2 + goff[3] + 4);
    }

    // ------- proj (swapped: D lane = token, rows = e-quad), float4 stores -------
    {
      f32x4 pa0[4], pa1[4];
#pragma unroll
      for (int nt = 0; nt < 4; ++nt) { pa0[nt] = vzero; pa1[nt] = vzero; }
#pragma unroll
      for (int ks = 0; ks < 6; ++ks) {
        const _Float16* bb = (ks & 1) ? bxb1 : bxb0;
        f16x8 a[4];
#pragma unroll
        for (int nt = 0; nt < 4; ++nt)
          a[nt] = ld8(bb + ks * 2048 + nt * 128);
        f16x8 w0, w1;
        if constexpr (WS) { w0 = ld8(pw0 + ks * 32); w1 = ld8(pw1 + ks * 32); }
        else              { w0 = cvt8(fw0 + ks * 32); w1 = cvt8(fw1 + ks * 32); }
        __builtin_amdgcn_s_setprio(1);
#pragma unroll
        for (int nt = 0; nt < 4; ++nt) {
          pa0[nt] = __builtin_amdgcn_mfma_f32_16x16x32_f16(w0, a[nt], pa0[nt], 0, 0, 0);
          pa1[nt] = __builtin_amdgcn_mfma_f32_16x16x32_f16(w1, a[nt], pa1[nt], 0, 0, 0);
        }
        __builtin_amdgcn_s_setprio(0);
      }
      float* outw = out + (size_t)win * (TOK * CDIM);
      float4 bp0 = *reinterpret_cast<const float4*>(b_proj + h * 16 + lg * 4);
      float4 bp1 = *reinterpret_cast<const float4*>(b_proj + h * 16 + 96 + lg * 4);
#pragma unroll
      for (int nt = 0; nt < 4; ++nt) {
        float4 r0, r1;
        r0.x = pa0[nt][0] + bp0.x; r0.y = pa0[nt][1] + bp0.y;
        r0.z = pa0[nt][2] + bp0.z; r0.w = pa0[nt][3] + bp0.w;
        r1.x = pa1[nt][0] + bp1.x; r1.y = pa1[nt][1] + bp1.y;
        r1.z = pa1[nt][2] + bp1.z; r1.w = pa1[nt][3] + bp1.w;
        float* rowp = outw + (nt * 16 + l15) * CDIM + h * 16 + lg * 4;
        *reinterpret_cast<float4*>(rowp) = r0;
        *reinterpret_cast<float4*>(rowp + 96) = r1;
      }
    }

    // ------- write prefetched x into the other buffer -------
    if (win2 < B) {
      _Float16* Xn = X[p ^ 1];
      *reinterpret_cast<f16x8*>(&Xn[soff[0]]) = cvt2(pf0a, pf0b);
      *reinterpret_cast<f16x8*>(&Xn[soff[1]]) = cvt2(pf1a, pf1b);
      *reinterpret_cast<f16x8*>(&Xn[soff[2]]) = cvt2(pf2a, pf2b);
      *reinterpret_cast<f16x8*>(&Xn[soff[3]]) = cvt2(pf3a, pf3b);
    }
    __syncthreads();  // b3: next x staged; Xa proj-reads done
    p ^= 1;
  }
}

extern "C" void kernel_launch(void* const* d_in, const int* in_sizes, int n_in,
                              void* d_out, int out_size, void* d_ws, size_t ws_size,
                              hipStream_t stream) {
  const float* x          = (const float*)d_in[0];
  const float* w_qkv      = (const float*)d_in[1];
  const float* b_qkv      = (const float*)d_in[2];
  const float* w_proj     = (const float*)d_in[3];
  const float* b_proj     = (const float*)d_in[4];
  const float* bias_table = (const float*)d_in[5];
  float* out = (float*)d_out;
  int B = in_sizes[0] / (TOK * CDIM);
  int G = B < GRID_MAX ? B : GRID_MAX;

  if (ws_size >= (size_t)WS_BYTES) {
    _Float16* ws = (_Float16*)d_ws;
    hipLaunchKernelGGL(prep_ws, dim3(240), dim3(256), 0, stream,
                       w_qkv, w_proj, bias_table, ws);
    hipLaunchKernelGGL(winattn<true>, dim3(G), dim3(THREADS), 0, stream,
                       x, w_qkv, b_qkv, w_proj, b_proj, bias_table, ws, out, B);
  } else {
    hipLaunchKernelGGL(winattn<false>, dim3(G), dim3(THREADS), 0, stream,
                       x, w_qkv, b_qkv, w_proj, b_proj, bias_table,
                       (const _Float16*)nullptr, out, B);
  }
}

// Round 14
// 240.118 us; speedup vs baseline: 1.9774x; 1.9774x over previous
//
#include <hip/hip_runtime.h>

#define TOK 64
#define CDIM 192
#define NH 6
#define HD 32
#define THREADS 384
#define QSCALE 0.17677669529663687f  // 32^-0.5

// workspace layout (halfs): w_qkv16 [576*192] | w_proj16 [192*192] | bias frags [6*4*64*16]
#define WQ16_OFF 0
#define WP16_OFF 110592
#define BIAS_OFF 147456
#define WS_HALFS (147456 + 24576)
#define WS_BYTES (WS_HALFS * 2)

typedef _Float16 f16x8 __attribute__((ext_vector_type(8)));
typedef _Float16 f16x4 __attribute__((ext_vector_type(4)));
typedef float f32x4 __attribute__((ext_vector_type(4)));

__device__ __forceinline__ f16x8 ld8(const _Float16* p) {
  return *reinterpret_cast<const f16x8*>(p);
}
__device__ __forceinline__ f16x4 ld4(const _Float16* p) {
  return *reinterpret_cast<const f16x4*>(p);
}

__device__ __forceinline__ f16x8 cvt8(const float* __restrict__ p) {
  float4 a = *reinterpret_cast<const float4*>(p);
  float4 c = *reinterpret_cast<const float4*>(p + 4);
  f16x8 r;
  r[0] = (_Float16)a.x; r[1] = (_Float16)a.y; r[2] = (_Float16)a.z; r[3] = (_Float16)a.w;
  r[4] = (_Float16)c.x; r[5] = (_Float16)c.y; r[6] = (_Float16)c.z; r[7] = (_Float16)c.w;
  return r;
}

__device__ __forceinline__ f16x4 pack4(float a, float b, float c, float d) {
  f16x4 r;
  r[0] = (_Float16)a; r[1] = (_Float16)b; r[2] = (_Float16)c; r[3] = (_Float16)d;
  return r;
}

// Prologue: fp16 weights + per-(head,row-tile) bias fragments (two f16x8 per lane).
__global__ void prep_ws(const float* __restrict__ wq, const float* __restrict__ wp,
                        const float* __restrict__ bt, _Float16* __restrict__ ws) {
  int i = blockIdx.x * 256 + threadIdx.x;
  if (i < 27648) {
    float4 v = reinterpret_cast<const float4*>(wq)[i];
    f16x4 h;
    h[0] = (_Float16)v.x; h[1] = (_Float16)v.y; h[2] = (_Float16)v.z; h[3] = (_Float16)v.w;
    *reinterpret_cast<f16x4*>(ws + WQ16_OFF + (size_t)i * 4) = h;
  } else if (i < 36864) {
    int j = i - 27648;
    float4 v = reinterpret_cast<const float4*>(wp)[j];
    f16x4 h;
    h[0] = (_Float16)v.x; h[1] = (_Float16)v.y; h[2] = (_Float16)v.z; h[3] = (_Float16)v.w;
    *reinterpret_cast<f16x4*>(ws + WP16_OFF + (size_t)j * 4) = h;
  } else if (i < 61440) {
    int j = i - 36864;            // ((h*4+it)*64 + lane)*16 + (jt*4+r)
    int hit = j >> 10;
    int l = (j >> 4) & 63;
    int s = j & 15;
    int h = hit >> 2, it = hit & 3;
    int ii = it * 16 + (l & 15);
    int jj = (s >> 2) * 16 + (l >> 4) * 4 + (s & 3);
    int rel = ((ii >> 3) - (jj >> 3) + 7) * 15 + ((ii & 7) - (jj & 7) + 7);
    ws[BIAS_OFF + j] = (_Float16)bt[rel * NH + h];
  }
}

// Transpose-free fused window attention, kp-spilled-to-LDS edition.
// 1 block = 1 window, 6 waves (1 head each), 48 KB LDS (24 x/O + 24 KP),
// 3 barriers, __launch_bounds__(384,5) = 102-reg budget -> 3 blocks/CU
// (144 KB LDS, 18 waves/CU). The packed k fragments (16 VGPRs in rounds
// 9-12, which pushed alloc to ~104 > the 102 step) live in a wave-private
// LDS region instead: f16x4 per lane, 64 lanes x 8B contiguous ->
// conflict-free, same-wave RAW needs no barrier. Phase peaks now <= ~88.
// Key identity (mfma_f32_16x16x16_f16): A/B k-slice per lane ((l>>4)*4..+3)
// equals D-row indexing -> packed D fragments feed attention MFMAs directly:
//   q,k: swapped GEMM (D lane = token, rows = d) -> QK^T operands, no shuffle.
//   S:   lane = q-token, rows = kv -> in-lane softmax (+2 shfl_xor).
//   v:   standard GEMM (D lane = d, rows = kv)  -> PV B-frag.
// Proj swapped (round 13, verified): D lane = token, rows = e-quad ->
// coalesced 64B float4 stores.
template <bool WS>
__global__ __launch_bounds__(THREADS, 5) void winattn(
    const float* __restrict__ x, const float* __restrict__ w_qkv,
    const float* __restrict__ b_qkv, const float* __restrict__ w_proj,
    const float* __restrict__ b_proj, const float* __restrict__ bias_table,
    const _Float16* __restrict__ ws, float* __restrict__ out) {
  __shared__ __align__(16) _Float16 R1[12288];  // x panels -> O panels
  __shared__ __align__(16) _Float16 KP[12288];  // packed k frags [h][frag8][lane64][4]

  const int tid = threadIdx.x;
  const int h   = tid >> 6;   // wave == head (0..5)
  const int l   = tid & 63;
  const int l15 = l & 15;
  const int lg  = l >> 4;
  const int b   = blockIdx.x;
  const int sA0 = l15 ^ lg;
  const int sA1 = sA0 ^ 4;
  const f32x4 vzero = {0.f, 0.f, 0.f, 0.f};

  // ---------------- stage x (fp32 -> fp16 swizzled panels) ----------------
  const float* xg = x + (size_t)b * (TOK * CDIM);
#pragma unroll
  for (int kk = 0; kk < 4; ++kk) {
    int q = tid + kk * THREADS;
    int n = q / 24;              // token
    int p = q - n * 24;          // c-panel
    const float* src = xg + q * 8;
    float4 v0 = *reinterpret_cast<const float4*>(src);
    float4 v1 = *reinterpret_cast<const float4*>(src + 4);
    f16x8 h8;
    h8[0] = (_Float16)v0.x; h8[1] = (_Float16)v0.y;
    h8[2] = (_Float16)v0.z; h8[3] = (_Float16)v0.w;
    h8[4] = (_Float16)v1.x; h8[5] = (_Float16)v1.y;
    h8[6] = (_Float16)v1.z; h8[7] = (_Float16)v1.w;
    *reinterpret_cast<f16x8*>(&R1[(p * TOK + (n ^ (p & 7))) * 8]) = h8;
  }
  __syncthreads();  // b0

  const _Float16* bxb0 = &R1[(lg * TOK + sA0) * 8];
  const _Float16* bxb1 = &R1[(lg * TOK + sA1) * 8];
  _Float16* kpb = &KP[(size_t)h * 2048 + l * 4];  // frag f at + f*256

  // ------- q GEMM, swapped: D lane = token, rows = d -------
  f16x4 qp[2][4];  // packed q: [d-step][token-tile] (held through attention)
  {
    f32x4 aq[2][4];
#pragma unroll
    for (int mt = 0; mt < 2; ++mt)
#pragma unroll
      for (int nt = 0; nt < 4; ++nt) aq[mt][nt] = vzero;
#pragma unroll
    for (int ks = 0; ks < 6; ++ks) {
      const _Float16* bb = (ks & 1) ? bxb1 : bxb0;
      f16x8 bx[4];
#pragma unroll
      for (int nt = 0; nt < 4; ++nt)
        bx[nt] = ld8(bb + ks * 2048 + nt * 128);
      f16x8 aw[2];
#pragma unroll
      for (int mt = 0; mt < 2; ++mt) {
        int row = h * HD + mt * 16 + l15;
        if constexpr (WS) aw[mt] = ld8(ws + WQ16_OFF + (size_t)row * CDIM + ks * 32 + lg * 8);
        else              aw[mt] = cvt8(w_qkv + (size_t)row * CDIM + ks * 32 + lg * 8);
      }
      __builtin_amdgcn_s_setprio(1);
#pragma unroll
      for (int mt = 0; mt < 2; ++mt)
#pragma unroll
        for (int nt = 0; nt < 4; ++nt)
          aq[mt][nt] = __builtin_amdgcn_mfma_f32_16x16x32_f16(aw[mt], bx[nt], aq[mt][nt], 0, 0, 0);
      __builtin_amdgcn_s_setprio(0);
    }
#pragma unroll
    for (int mt = 0; mt < 2; ++mt) {
      float4 bq = *reinterpret_cast<const float4*>(b_qkv + h * HD + mt * 16 + lg * 4);
#pragma unroll
      for (int nt = 0; nt < 4; ++nt)
        qp[mt][nt] = pack4((aq[mt][nt][0] + bq.x) * QSCALE, (aq[mt][nt][1] + bq.y) * QSCALE,
                           (aq[mt][nt][2] + bq.z) * QSCALE, (aq[mt][nt][3] + bq.w) * QSCALE);
    }
  }

  // ------- k GEMM, swapped; packed frags spill to wave-private LDS -------
  {
    f32x4 ak[2][4];
#pragma unroll
    for (int mt = 0; mt < 2; ++mt)
#pragma unroll
      for (int nt = 0; nt < 4; ++nt) ak[mt][nt] = vzero;
#pragma unroll
    for (int ks = 0; ks < 6; ++ks) {
      const _Float16* bb = (ks & 1) ? bxb1 : bxb0;
      f16x8 bx[4];
#pragma unroll
      for (int nt = 0; nt < 4; ++nt)
        bx[nt] = ld8(bb + ks * 2048 + nt * 128);
      f16x8 aw[2];
#pragma unroll
      for (int mt = 0; mt < 2; ++mt) {
        int row = CDIM + h * HD + mt * 16 + l15;
        if constexpr (WS) aw[mt] = ld8(ws + WQ16_OFF + (size_t)row * CDIM + ks * 32 + lg * 8);
        else              aw[mt] = cvt8(w_qkv + (size_t)row * CDIM + ks * 32 + lg * 8);
      }
      __builtin_amdgcn_s_setprio(1);
#pragma unroll
      for (int mt = 0; mt < 2; ++mt)
#pragma unroll
        for (int nt = 0; nt < 4; ++nt)
          ak[mt][nt] = __builtin_amdgcn_mfma_f32_16x16x32_f16(aw[mt], bx[nt], ak[mt][nt], 0, 0, 0);
      __builtin_amdgcn_s_setprio(0);
    }
#pragma unroll
    for (int mt = 0; mt < 2; ++mt) {
      float4 bk = *reinterpret_cast<const float4*>(b_qkv + CDIM + h * HD + mt * 16 + lg * 4);
#pragma unroll
      for (int nt = 0; nt < 4; ++nt) {
        f16x4 t = pack4(ak[mt][nt][0] + bk.x, ak[mt][nt][1] + bk.y,
                        ak[mt][nt][2] + bk.z, ak[mt][nt][3] + bk.w);
        *reinterpret_cast<f16x4*>(kpb + (mt * 4 + nt) * 256) = t;
      }
    }
  }

  // ------- v GEMM, standard (lane = d, rows = kv), both ct merged -------
  f16x4 vp[4][2];  // packed v: [kv-step][d-tile] (held through attention)
  {
    f32x4 av[4][2];
#pragma unroll
    for (int mt = 0; mt < 4; ++mt)
#pragma unroll
      for (int ct = 0; ct < 2; ++ct) av[mt][ct] = vzero;
#pragma unroll
    for (int ks = 0; ks < 6; ++ks) {
      const _Float16* bb = (ks & 1) ? bxb1 : bxb0;
      f16x8 a[4];
#pragma unroll
      for (int mt = 0; mt < 4; ++mt)
        a[mt] = ld8(bb + ks * 2048 + mt * 128);
      f16x8 bw[2];
#pragma unroll
      for (int ct = 0; ct < 2; ++ct) {
        int col = 2 * CDIM + h * HD + ct * 16 + l15;
        if constexpr (WS) bw[ct] = ld8(ws + WQ16_OFF + (size_t)col * CDIM + ks * 32 + lg * 8);
        else              bw[ct] = cvt8(w_qkv + (size_t)col * CDIM + ks * 32 + lg * 8);
      }
      __builtin_amdgcn_s_setprio(1);
#pragma unroll
      for (int mt = 0; mt < 4; ++mt)
#pragma unroll
        for (int ct = 0; ct < 2; ++ct)
          av[mt][ct] = __builtin_amdgcn_mfma_f32_16x16x32_f16(a[mt], bw[ct], av[mt][ct], 0, 0, 0);
      __builtin_amdgcn_s_setprio(0);
    }
    float bv0 = b_qkv[2 * CDIM + h * HD + l15];
    float bv1 = b_qkv[2 * CDIM + h * HD + 16 + l15];
#pragma unroll
    for (int s = 0; s < 4; ++s) {
      vp[s][0] = pack4(av[s][0][0] + bv0, av[s][0][1] + bv0, av[s][0][2] + bv0, av[s][0][3] + bv0);
      vp[s][1] = pack4(av[s][1][0] + bv1, av[s][1][1] + bv1, av[s][1][2] + bv1, av[s][1][3] + bv1);
    }
  }
  __syncthreads();  // b1: all x reads done -> R1 free for O

  // ---------------- attention: 4 row-tiles, in-register ----------------
#pragma unroll
  for (int it = 0; it < 4; ++it) {
    f32x4 st[4];  // S: lane = q-token (it*16+l15), rows = kv = jt*16+lg*4+r
    __builtin_amdgcn_s_setprio(1);
#pragma unroll
    for (int jt = 0; jt < 4; ++jt) {
      f16x4 k0 = ld4(kpb + jt * 256);        // kp[0][jt]
      f16x4 k1 = ld4(kpb + (4 + jt) * 256);  // kp[1][jt]
      st[jt] = __builtin_amdgcn_mfma_f32_16x16x16f16(k0, qp[0][it], vzero, 0, 0, 0);
      st[jt] = __builtin_amdgcn_mfma_f32_16x16x16f16(k1, qp[1][it], st[jt], 0, 0, 0);
    }
    __builtin_amdgcn_s_setprio(0);
    // bias
    if constexpr (WS) {
      const _Float16* bw = ws + BIAS_OFF + ((h * 4 + it) * 64 + l) * 16;
      f16x8 b0 = ld8(bw), b1 = ld8(bw + 8);
#pragma unroll
      for (int jt = 0; jt < 4; ++jt)
#pragma unroll
        for (int r = 0; r < 4; ++r)
          st[jt][r] += (float)((jt < 2) ? b0[jt * 4 + r] : b1[(jt - 2) * 4 + r]);
    } else {
      int i = it * 16 + l15, yi = i >> 3, xi = i & 7;
#pragma unroll
      for (int jt = 0; jt < 4; ++jt)
#pragma unroll
        for (int r = 0; r < 4; ++r) {
          int j = jt * 16 + lg * 4 + r, yj = j >> 3, xj = j & 7;
          st[jt][r] += bias_table[(((yi - yj + 7) * 15 + (xi - xj + 7)) * NH + h)];
        }
    }
    // softmax over kv: 16 in-lane + cross-lg (xor 16, 32)
    float m = st[0][0];
#pragma unroll
    for (int jt = 0; jt < 4; ++jt)
#pragma unroll
      for (int r = 0; r < 4; ++r) m = fmaxf(m, st[jt][r]);
    m = fmaxf(m, __shfl_xor(m, 16, 64));
    m = fmaxf(m, __shfl_xor(m, 32, 64));
    float sum = 0.f;
#pragma unroll
    for (int jt = 0; jt < 4; ++jt)
#pragma unroll
      for (int r = 0; r < 4; ++r) { st[jt][r] = __expf(st[jt][r] - m); sum += st[jt][r]; }
    sum += __shfl_xor(sum, 16, 64);
    sum += __shfl_xor(sum, 32, 64);
    float inv = 1.f / sum;
    // P pack (in-lane) + PV
    f32x4 o[2] = {vzero, vzero};
#pragma unroll
    for (int s = 0; s < 4; ++s) {
      f16x4 pp = pack4(st[s][0] * inv, st[s][1] * inv, st[s][2] * inv, st[s][3] * inv);
      __builtin_amdgcn_s_setprio(1);
      o[0] = __builtin_amdgcn_mfma_f32_16x16x16f16(pp, vp[s][0], o[0], 0, 0, 0);
      o[1] = __builtin_amdgcn_mfma_f32_16x16x16f16(pp, vp[s][1], o[1], 0, 0, 0);
      __builtin_amdgcn_s_setprio(0);
    }
    // O -> R1 swizzled panels (lane = d col, rows = q-token it*16+lg*4+r)
#pragma unroll
    for (int ct = 0; ct < 2; ++ct) {
      int c = h * HD + ct * 16 + l15;
      int op = c >> 3, s7 = op & 7;
      int lgx = lg ^ (s7 >> 2);
      int base = (op * TOK + it * 16 + lgx * 4) * 8 + (c & 7);
#pragma unroll
      for (int r = 0; r < 4; ++r)
        R1[base + (r ^ (s7 & 3)) * 8] = (_Float16)o[ct][r];
    }
  }
  __syncthreads();  // b2: O visible

  // ------- proj (swapped: D lane = token, rows = e-quad), float4 stores -------
  {
    f32x4 pa0[4], pa1[4];
#pragma unroll
    for (int nt = 0; nt < 4; ++nt) { pa0[nt] = vzero; pa1[nt] = vzero; }
#pragma unroll
    for (int ks = 0; ks < 6; ++ks) {
      const _Float16* bb = (ks & 1) ? bxb1 : bxb0;
      f16x8 a[4];
#pragma unroll
      for (int nt = 0; nt < 4; ++nt)
        a[nt] = ld8(bb + ks * 2048 + nt * 128);
      f16x8 w0, w1;
      if constexpr (WS) {
        w0 = ld8(ws + WP16_OFF + (size_t)(h * 16 + l15) * CDIM + ks * 32 + lg * 8);
        w1 = ld8(ws + WP16_OFF + (size_t)(h * 16 + 96 + l15) * CDIM + ks * 32 + lg * 8);
      } else {
        w0 = cvt8(w_proj + (size_t)(h * 16 + l15) * CDIM + ks * 32 + lg * 8);
        w1 = cvt8(w_proj + (size_t)(h * 16 + 96 + l15) * CDIM + ks * 32 + lg * 8);
      }
      __builtin_amdgcn_s_setprio(1);
#pragma unroll
      for (int nt = 0; nt < 4; ++nt) {
        pa0[nt] = __builtin_amdgcn_mfma_f32_16x16x32_f16(w0, a[nt], pa0[nt], 0, 0, 0);
        pa1[nt] = __builtin_amdgcn_mfma_f32_16x16x32_f16(w1, a[nt], pa1[nt], 0, 0, 0);
      }
      __builtin_amdgcn_s_setprio(0);
    }
    float* outw = out + (size_t)b * (TOK * CDIM);
    float4 bp0 = *reinterpret_cast<const float4*>(b_proj + h * 16 + lg * 4);
    float4 bp1 = *reinterpret_cast<const float4*>(b_proj + h * 16 + 96 + lg * 4);
#pragma unroll
    for (int nt = 0; nt < 4; ++nt) {
      float4 r0, r1;
      r0.x = pa0[nt][0] + bp0.x; r0.y = pa0[nt][1] + bp0.y;
      r0.z = pa0[nt][2] + bp0.z; r0.w = pa0[nt][3] + bp0.w;
      r1.x = pa1[nt][0] + bp1.x; r1.y = pa1[nt][1] + bp1.y;
      r1.z = pa1[nt][2] + bp1.z; r1.w = pa1[nt][3] + bp1.w;
      float* rowp = outw + (nt * 16 + l15) * CDIM + h * 16 + lg * 4;
      *reinterpret_cast<float4*>(rowp) = r0;
      *reinterpret_cast<float4*>(rowp + 96) = r1;
    }
  }
}

extern "C" void kernel_launch(void* const* d_in, const int* in_sizes, int n_in,
                              void* d_out, int out_size, void* d_ws, size_t ws_size,
                              hipStream_t stream) {
  const float* x          = (const float*)d_in[0];
  const float* w_qkv      = (const float*)d_in[1];
  const float* b_qkv      = (const float*)d_in[2];
  const float* w_proj     = (const float*)d_in[3];
  const float* b_proj     = (const float*)d_in[4];
  const float* bias_table = (const float*)d_in[5];
  float* out = (float*)d_out;
  int B = in_sizes[0] / (TOK * CDIM);

  if (ws_size >= (size_t)WS_BYTES) {
    _Float16* ws = (_Float16*)d_ws;
    hipLaunchKernelGGL(prep_ws, dim3(240), dim3(256), 0, stream,
                       w_qkv, w_proj, bias_table, ws);
    hipLaunchKernelGGL(winattn<true>, dim3(B), dim3(THREADS), 0, stream,
                       x, w_qkv, b_qkv, w_proj, b_proj, bias_table, ws, out);
  } else {
    hipLaunchKernelGGL(winattn<false>, dim3(B), dim3(THREADS), 0, stream,
                       x, w_qkv, b_qkv, w_proj, b_proj, bias_table,
                       (const _Float16*)nullptr, out);
  }
}